// Round 6
// baseline (107.527 us; speedup 1.0000x reference)
//
#include <hip/hip_runtime.h>

// RelativePositionEncoding (AF3-style), B=1, N=1024, C_PAIR=128
// W rows: Wp = 0..65, Wt = 66..131, w_ent = 132, Wc = 133..138 (D_IN = 139)

#define C_PAIR 128
#define N_COMBO 152
#define NTOK 1024
#define ISEG 4
#define JSEG 64

typedef float f4 __attribute__((ext_vector_type(4)));

// combo id encoding (covers every reachable (idx_pos, idx_tok, idx_chain, se)):
//   same-chain & same-residue : cid = clamp(ti-tj+32,0,64) + se*65            -> [0,129]
//   same-chain & !same-residue: cid = 130 + se                                -> [130,131]
//   diff-chain                : cid = 132 + clamp(si-sj+2,0,4) + sr*5 + se*10 -> [132,151]
__device__ __forceinline__ int combo_id(int ri, int ai, int ei, int ti, int si,
                                        int rj, int aj, int ej, int tj, int sj) {
    const bool sr = (ri == rj);
    const bool sc = (ai == aj);
    const bool se = (ei == ej);
    int cid;
    if (sc) {
        if (sr) {
            int dt = ti - tj + 32;
            dt = dt < 0 ? 0 : (dt > 64 ? 64 : dt);
            cid = dt + (se ? 65 : 0);
        } else {
            cid = 130 + (se ? 1 : 0);
        }
    } else {
        int dc = si - sj + 2;
        dc = dc < 0 ? 0 : (dc > 4 ? 4 : dc);
        cid = 132 + dc + (sr ? 5 : 0) + (se ? 10 : 0);
    }
    return cid;
}

// Pass 1: build combined table T[cid][c] = ((Wp + Wt) + se*w_ent) + Wc
// (same fp32 add order as the reference -> bit-identical)
__global__ __launch_bounds__(128) void rpe_combine(const float* __restrict__ W,
                                                   float* __restrict__ T) {
    const int cid = blockIdx.x;
    const int c   = threadIdx.x;
    int idx_pos, idx_tok, idx_chain, se;
    if (cid < 130) {
        se = cid >= 65 ? 1 : 0;
        idx_pos = 32; idx_tok = cid - se * 65; idx_chain = 5;
    } else if (cid < 132) {
        se = cid - 130;
        idx_pos = 65; idx_tok = 65; idx_chain = 5;
    } else {
        int r = cid - 132;
        se = r >= 10 ? 1 : 0; r -= se * 10;
        const int sr = r >= 5 ? 1 : 0; r -= sr * 5;
        idx_pos = sr ? 32 : 65; idx_tok = 65; idx_chain = r;
    }
    const float p  = W[idx_pos * C_PAIR + c];
    const float t  = W[(66 + idx_tok) * C_PAIR + c];
    const float e  = W[132 * C_PAIR + c];
    const float ch = W[(133 + idx_chain) * C_PAIR + c];
    const float fe = se ? 1.0f : 0.0f;
    T[cid * C_PAIR + c] = ((p + t) + fe * e) + ch;
}

// Pass 2: 4 rows x 64 j per block (128 KB stored / block), 4096 blocks.
// Prologue: 256 threads compute 256 cids in parallel (one each) -> LDS u16.
// Store loop: 32 iters of { ds_read_u16 + 1 T-load (L1/L2) + 1 nt 16B store }.
__global__ __launch_bounds__(256) void rpe_apply4x64(
    const int* __restrict__ res, const int* __restrict__ tok,
    const int* __restrict__ asym, const int* __restrict__ ent,
    const int* __restrict__ sym, const float* __restrict__ T,
    float* __restrict__ out)
{
    __shared__ unsigned short s_cid[ISEG * JSEG];   // 512 B

    const int bid  = blockIdx.x;
    const int nseg = NTOK / JSEG;                   // 16
    const int i0   = (bid / nseg) * ISEG;
    const int j0   = (bid % nseg) * JSEG;
    const int t    = threadIdx.x;

    // prologue: thread t -> (ii = t>>6, jj = t&63), all threads busy
    {
        const int ii = t >> 6, jj = t & 63;
        const int i = i0 + ii, j = j0 + jj;
        s_cid[ii * JSEG + jj] = (unsigned short)combo_id(
            res[i], asym[i], ent[i], tok[i], sym[i],
            res[j], asym[j], ent[j], tok[j], sym[j]);
    }
    __syncthreads();

    const int sub = t >> 5;                         // 0..7 (j within group of 8)
    const int ch  = t & 31;                         // f4 chunk
    #pragma unroll 8
    for (int it = 0; it < 32; ++it) {
        const int ii = it >> 3;                     // row 0..3
        const int jb = it & 7;                      // j-octet 0..7
        const int j  = jb * 8 + sub;                // 0..63 within segment
        const int cid = s_cid[ii * JSEG + j];
        const f4 v = ((const f4*)(T + (size_t)cid * C_PAIR))[ch];
        __builtin_nontemporal_store(
            v, (f4*)out + (((size_t)(i0 + ii) * NTOK) + j0 + j) * 32 + ch);
    }
}

// Fallback for unexpected N (direct 4-load version, round-1 kernel)
__global__ __launch_bounds__(256) void rpe_direct(
    const int* __restrict__ res, const int* __restrict__ tok,
    const int* __restrict__ asym, const int* __restrict__ ent,
    const int* __restrict__ sym, const float* __restrict__ W,
    float* __restrict__ out, int N, int blocks_per_row)
{
    const int bid = blockIdx.x;
    const int i  = bid / blocks_per_row;
    const int jb = bid - i * blocks_per_row;
    const int t  = threadIdx.x;
    const int j  = jb * 8 + (t >> 5);
    const int c4 = t & 31;

    const int ri = res[i],  rj = res[j];
    const int ai = asym[i], aj = asym[j];
    const int ei = ent[i],  ej = ent[j];
    const int ti = tok[i],  tj = tok[j];
    const int si = sym[i],  sj = sym[j];

    const bool sr = (ri == rj);
    const bool sc = (ai == aj);
    const bool se = (ei == ej);

    const int idx_pos = sr ? 32 : 65;
    int dt = ti - tj + 32; dt = dt < 0 ? 0 : (dt > 64 ? 64 : dt);
    const int idx_tok = (sr && sc) ? dt : 65;
    int dc = si - sj + 2; dc = dc < 0 ? 0 : (dc > 4 ? 4 : dc);
    const int idx_chain = (!sc) ? dc : 5;

    const f4 p  = ((const f4*)(W + (size_t)idx_pos * C_PAIR))[c4];
    const f4 tk = ((const f4*)(W + (size_t)(66 + idx_tok) * C_PAIR))[c4];
    const f4 e  = ((const f4*)(W + (size_t)132 * C_PAIR))[c4];
    const f4 c  = ((const f4*)(W + (size_t)(133 + idx_chain) * C_PAIR))[c4];
    const float fe = se ? 1.0f : 0.0f;

    f4 r;
    r.x = ((p.x + tk.x) + fe * e.x) + c.x;
    r.y = ((p.y + tk.y) + fe * e.y) + c.y;
    r.z = ((p.z + tk.z) + fe * e.z) + c.z;
    r.w = ((p.w + tk.w) + fe * e.w) + c.w;

    ((f4*)(out + ((size_t)i * N + j) * C_PAIR))[c4] = r;
}

extern "C" void kernel_launch(void* const* d_in, const int* in_sizes, int n_in,
                              void* d_out, int out_size, void* d_ws, size_t ws_size,
                              hipStream_t stream) {
    const int* res  = (const int*)d_in[0];
    const int* tok  = (const int*)d_in[1];
    const int* asym = (const int*)d_in[2];
    const int* ent  = (const int*)d_in[3];
    const int* sym  = (const int*)d_in[4];
    const float* W  = (const float*)d_in[5];
    float* out = (float*)d_out;

    const int N = in_sizes[0];
    const size_t table_bytes = (size_t)N_COMBO * C_PAIR * sizeof(float);

    if (N == NTOK && ws_size >= table_bytes) {
        float* T = (float*)d_ws;
        rpe_combine<<<N_COMBO, 128, 0, stream>>>(W, T);
        const int grid = (NTOK / ISEG) * (NTOK / JSEG);   // 4096
        rpe_apply4x64<<<grid, 256, 0, stream>>>(res, tok, asym, ent, sym, T, out);
    } else {
        const int blocks_per_row = N / 8;
        rpe_direct<<<N * blocks_per_row, 256, 0, stream>>>(res, tok, asym, ent, sym,
                                                           W, out, N, blocks_per_row);
    }
}